// Round 2
// baseline (1193.139 us; speedup 1.0000x reference)
//
#include <hip/hip_runtime.h>
#include <math.h>

// FICONN photonic NN forward: 5 complex 64x64 unitary layers + nofu nonlinearity + 3-layer MLP.
// fp32 VALU implementation (no fp32 MFMA on CDNA4). Compute-bound ~48 GFLOP.
//
// R2 changes vs R1 (773 us main):
//  - LDS 49.6KB -> 33.3KB (split h1 MLP stage into two 64-row halves): 3 -> 4 blocks/CU.
//  - Layer 0 treats input as real (imag==0): 32 FMA/j instead of 64 (-10% FLOP).
//  - nofu per-row constants (sigmoid/sqrt/sens*beta) precomputed once in prep; v_rcp div.
//  - float4 x-tile load; j-loops unroll 4.
//  - prep merged into build kernel (one fewer launch); cos/sin table as float4 (ds_read_b128);
//    build gets __launch_bounds__(64,1) so the unrolled scan can pipeline.

#define NN 64
#define LL 5
#define NMZI 2016            // 64*63/2
#define C_HALF 0.7071067811865476f
#define GAMMA_ 0.05f
#define SENSRESP 0.0008f     // SENS*RESP

// workspace layout (float offsets)
#define UC_OFF   0                 // UC[l][c][r] float2: U[r][c]*e^{i psi_r}; 5*64*64*2 = 40960
#define W1T_OFF  40960             // W1T[j][r]  (64 x 128) = 8192
#define W2T_OFF  49152             // W2T[j][r]  (128 x 64) = 8192
#define W3T_OFF  57344             // W3T[j][r]  (64 x 12)  = 768
#define NOFU_OFF 58112             // 4 layers x 64 rows x float4 (sb, sq, d0, 0) = 1024

// ---------------------------------------------------------------------------
// Kernel 1: blocks 0-4 build the unitaries (thread = column, scan fully
// unrolled in registers); blocks 5-8 transpose MLP weights + nofu constants.
// ---------------------------------------------------------------------------
__global__ __launch_bounds__(64, 1) void build_all(
    const float* __restrict__ mzi, const float* __restrict__ oph,
    const float* __restrict__ W1, const float* __restrict__ W2,
    const float* __restrict__ W3, const float* __restrict__ beta_param,
    const float* __restrict__ det0, float* __restrict__ ws)
{
    __shared__ float4 cs4[NMZI];    // {cos(phi), sin(phi), C*cos(th), C*sin(th)}
    __shared__ float ocs[NN][2];    // {cos(psi), sin(psi)}

    if (blockIdx.x < 5) {
        const int l = blockIdx.x;
        const int c = threadIdx.x;

        for (int m = c; m < NMZI; m += 64) {
            float th = mzi[l * 2 * NMZI + 2 * m];
            float ph = mzi[l * 2 * NMZI + 2 * m + 1];
            float sth, cth, sph, cph;
            sincosf(th, &sth, &cth);
            sincosf(ph, &sph, &cph);
            cs4[m] = make_float4(cph, sph, C_HALF * cth, C_HALF * sth);
        }
        {
            float ps = oph[l * NN + c];
            float sp, cp; sincosf(ps, &sp, &cp);
            ocs[c][0] = cp; ocs[c][1] = sp;
        }
        __syncthreads();

        float ur[NN], ui[NN];
        #pragma unroll
        for (int r = 0; r < NN; ++r) { ur[r] = (r == c) ? 1.f : 0.f; ui[r] = 0.f; }

        int m = 0;
        #pragma unroll
        for (int i = 0; i < NN - 1; ++i) {
            #pragma unroll
            for (int j = i + 1; j < NN; ++j) {
                float4 q = cs4[m];
                float tr = q.x * ur[j] - q.y * ui[j];       // e^{i phi} u_j
                float ti = q.x * ui[j] + q.y * ur[j];
                float ar = ur[i] + tr, ai = ui[i] + ti;
                float sr = ur[i] - tr, si = ui[i] - ti;
                ur[i] = C_HALF * ar;
                ui[i] = C_HALF * ai;
                ur[j] = q.z * sr - q.w * si;                // C e^{i th} (u_i - t)
                ui[j] = q.z * si + q.w * sr;
                ++m;
            }
        }

        float* UCl = ws + UC_OFF + (l * NN + c) * NN * 2;
        #pragma unroll
        for (int r = 0; r < NN; ++r) {
            float cp = ocs[r][0], sp = ocs[r][1];
            UCl[2 * r]     = cp * ur[r] - sp * ui[r];
            UCl[2 * r + 1] = cp * ui[r] + sp * ur[r];
        }
    } else {
        const int tid = (blockIdx.x - 5) * 64 + threadIdx.x;   // 0..255
        // weight transposes (17152 elements, 256 threads)
        for (int idx = tid; idx < 17152; idx += 256) {
            if (idx < 8192) {                       // W1 (128,64) -> W1T[j][r]
                int r = idx >> 6, j = idx & 63;
                ws[W1T_OFF + j * 128 + r] = W1[idx];
            } else if (idx < 16384) {               // W2 (64,128) -> W2T[j][r]
                int t = idx - 8192;
                int r = t >> 7, j = t & 127;
                ws[W2T_OFF + j * 64 + r] = W2[t];
            } else {                                // W3 (12,64) -> W3T[j][r]
                int t = idx - 16384;
                int r = t >> 6, j = t & 63;
                ws[W3T_OFF + j * 12 + r] = W3[t];
            }
        }
        // nofu per-row constants: (sb = SENSRESP*beta, sq = sqrt(relu(1-beta))*gamma, d0, 0)
        if (tid < 256) {                            // tid = l*64 + row, l in [0,4)
            float bp = beta_param[tid];
            float beta = 1.f / (1.f + expf(-bp));
            float sb = SENSRESP * beta;
            float sq = sqrtf(fmaxf(1.f - beta, 0.f)) * GAMMA_;
            float* p = ws + NOFU_OFF + tid * 4;
            p[0] = sb; p[1] = sq; p[2] = det0[tid]; p[3] = 0.f;
        }
    }
}

// ---------------------------------------------------------------------------
// Kernel 2: main. 64 samples/block, 256 threads. lane = sample, wave w owns
// rows [16w,16w+16). Field in LDS (stride-65 SoA, conflict-free); U rows are
// wave-uniform contiguous runs -> scalar loads. LDS 33.3KB -> 4 blocks/CU.
// ---------------------------------------------------------------------------
__global__ __launch_bounds__(256, 4) void ficonn_main(
    const float* __restrict__ x,
    const float* __restrict__ b1,
    const float* __restrict__ b2,
    const float* __restrict__ b3,
    const float* __restrict__ ws,
    float* __restrict__ out)
{
    __shared__ float sA[4160];   // field re / power / h2   (stride 65)
    __shared__ float sB[4160];   // field im / h1-half      (stride 65)

    const int s = threadIdx.x & 63;
    const int w = __builtin_amdgcn_readfirstlane(threadIdx.x >> 6);
    const int base = blockIdx.x * 64;

    // load x tile: coalesced float4 global, conflict-free LDS (stride 65)
    {
        const float4* x4 = (const float4*)(x + (size_t)base * 64);
        #pragma unroll
        for (int it = 0; it < 4; ++it) {
            int idx = threadIdx.x + it * 256;       // 1024 float4
            int j4 = idx & 15, ss = idx >> 4;
            float4 v = x4[ss * 16 + j4];
            sA[(4 * j4 + 0) * 65 + ss] = v.x;
            sA[(4 * j4 + 1) * 65 + ss] = v.y;
            sA[(4 * j4 + 2) * 65 + ss] = v.z;
            sA[(4 * j4 + 3) * 65 + ss] = v.w;
        }
    }
    __syncthreads();

    float ar[16], ai[16];
    const float* UC = ws + UC_OFF;
    const float4* nofuC = (const float4*)(ws + NOFU_OFF);

    // ---- layer 0: input is real (imag == 0) -> 32 FMA per j-step ----
    {
        #pragma unroll
        for (int k = 0; k < 16; ++k) { ar[k] = 0.f; ai[k] = 0.f; }
        const float* Ul = UC + w * 32;
        #pragma unroll 4
        for (int j = 0; j < 64; ++j) {
            float fr = sA[j * 65 + s];
            const float* Uj = Ul + j * 128;
            #pragma unroll
            for (int k = 0; k < 16; ++k) {
                ar[k] = fmaf(Uj[2 * k],     fr, ar[k]);
                ai[k] = fmaf(Uj[2 * k + 1], fr, ai[k]);
            }
        }
        __syncthreads();
        #pragma unroll
        for (int k = 0; k < 16; ++k) {
            int row = w * 16 + k;
            float4 nc = nofuC[row];                 // l = 0
            float p   = fmaf(ar[k], ar[k], ai[k] * ai[k]);
            float det = fmaf(nc.x, p, nc.z);
            float den = fmaf(det, det, GAMMA_ * GAMMA_);
            float sc  = nc.y * __builtin_amdgcn_rcpf(den);
            sA[row * 65 + s] = sc * fmaf( det, ai[k], GAMMA_ * ar[k]);
            sB[row * 65 + s] = sc * fmaf(-det, ar[k], GAMMA_ * ai[k]);
        }
        __syncthreads();
    }

    // ---- layers 1..4: complex matvec ----
    for (int l = 1; l < LL; ++l) {
        #pragma unroll
        for (int k = 0; k < 16; ++k) { ar[k] = 0.f; ai[k] = 0.f; }
        const float* Ul = UC + l * 8192 + w * 32;
        #pragma unroll 4
        for (int j = 0; j < 64; ++j) {
            float fr = sA[j * 65 + s];
            float fi = sB[j * 65 + s];
            const float* Uj = Ul + j * 128;         // wave-uniform, contiguous
            #pragma unroll
            for (int k = 0; k < 16; ++k) {
                float cr = Uj[2 * k], ci = Uj[2 * k + 1];
                ar[k] = fmaf(cr, fr, fmaf(-ci, fi, ar[k]));
                ai[k] = fmaf(cr, fi, fmaf( ci, fr, ai[k]));
            }
        }
        __syncthreads();   // all reads of field done before overwrite

        if (l < LL - 1) {
            #pragma unroll
            for (int k = 0; k < 16; ++k) {
                int row = w * 16 + k;
                float4 nc = nofuC[l * 64 + row];
                float p   = fmaf(ar[k], ar[k], ai[k] * ai[k]);
                float det = fmaf(nc.x, p, nc.z);
                float den = fmaf(det, det, GAMMA_ * GAMMA_);
                float sc  = nc.y * __builtin_amdgcn_rcpf(den);
                sA[row * 65 + s] = sc * fmaf( det, ai[k], GAMMA_ * ar[k]);
                sB[row * 65 + s] = sc * fmaf(-det, ar[k], GAMMA_ * ai[k]);
            }
        } else {
            #pragma unroll
            for (int k = 0; k < 16; ++k) {
                int row = w * 16 + k;
                sA[row * 65 + s] = fmaf(ar[k], ar[k], ai[k] * ai[k]);  // power
            }
        }
        __syncthreads();
    }

    // ---- MLP: h1 in two 64-row halves (halves LDS vs R1) ----
    float g[16];
    #pragma unroll
    for (int k = 0; k < 16; ++k) g[k] = 0.f;

    #pragma unroll 1
    for (int half = 0; half < 2; ++half) {
        float h[16];
        #pragma unroll
        for (int k = 0; k < 16; ++k) h[k] = 0.f;
        // h1 rows r = 64*half + 16w + k
        const float* W1Tp = ws + W1T_OFF + 64 * half + w * 16;
        #pragma unroll 4
        for (int j = 0; j < 64; ++j) {
            float f = sA[j * 65 + s];               // power
            const float* r_ = W1Tp + j * 128;
            #pragma unroll
            for (int k = 0; k < 16; ++k) h[k] = fmaf(r_[k], f, h[k]);
        }
        #pragma unroll
        for (int k = 0; k < 16; ++k)
            sB[(w * 16 + k) * 65 + s] = fmaxf(h[k] + b1[64 * half + w * 16 + k], 0.f);
        __syncthreads();                            // h1 half ready

        // h2 partial: g += W2[:, 64*half : 64*half+64] @ h1_half
        const float* W2Tp = ws + W2T_OFF + (64 * half) * 64 + w * 16;
        #pragma unroll 4
        for (int j = 0; j < 64; ++j) {
            float f = sB[j * 65 + s];
            const float* r_ = W2Tp + j * 64;
            #pragma unroll
            for (int k = 0; k < 16; ++k) g[k] = fmaf(r_[k], f, g[k]);
        }
        __syncthreads();                            // done reading sB (and, half 1: sA)
    }

    // h2 -> sA (power dead)
    #pragma unroll
    for (int k = 0; k < 16; ++k)
        sA[(w * 16 + k) * 65 + s] = fmaxf(g[k] + b2[w * 16 + k], 0.f);
    __syncthreads();

    // out = W3 @ h2 + b3: wave w -> rows [3w, 3w+3)
    {
        float o0 = 0.f, o1 = 0.f, o2 = 0.f;
        const float* W3T = ws + W3T_OFF + w * 3;
        #pragma unroll 4
        for (int j = 0; j < 64; ++j) {
            float f = sA[j * 65 + s];
            const float* r_ = W3T + j * 12;
            o0 = fmaf(r_[0], f, o0);
            o1 = fmaf(r_[1], f, o1);
            o2 = fmaf(r_[2], f, o2);
        }
        float* op = out + (size_t)(base + s) * 12 + w * 3;
        op[0] = o0 + b3[w * 3 + 0];
        op[1] = o1 + b3[w * 3 + 1];
        op[2] = o2 + b3[w * 3 + 2];
    }
}

extern "C" void kernel_launch(void* const* d_in, const int* in_sizes, int n_in,
                              void* d_out, int out_size, void* d_ws, size_t ws_size,
                              hipStream_t stream)
{
    const float* x    = (const float*)d_in[0];
    const float* mzi  = (const float*)d_in[1];
    const float* oph  = (const float*)d_in[2];
    const float* beta = (const float*)d_in[3];
    const float* det0 = (const float*)d_in[4];
    const float* W1   = (const float*)d_in[5];
    const float* b1   = (const float*)d_in[6];
    const float* W2   = (const float*)d_in[7];
    const float* b2   = (const float*)d_in[8];
    const float* W3   = (const float*)d_in[9];
    const float* b3   = (const float*)d_in[10];
    float* ws  = (float*)d_ws;
    float* out = (float*)d_out;

    const int B = in_sizes[0] / NN;       // 262144
    const int blocks = B / 64;            // 4096

    hipLaunchKernelGGL(build_all, dim3(9), dim3(64), 0, stream,
                       mzi, oph, W1, W2, W3, beta, det0, ws);
    hipLaunchKernelGGL(ficonn_main, dim3(blocks), dim3(256), 0, stream,
                       x, b1, b2, b3, ws, out);
}

// Round 3
// 1011.227 us; speedup vs baseline: 1.1799x; 1.1799x over previous
//
#include <hip/hip_runtime.h>
#include <math.h>

// FICONN photonic NN forward: 5 complex 64x64 unitary layers + nofu nonlinearity + 3-layer MLP.
// fp32 VALU implementation (no fp32 MFMA on CDNA4). Compute-bound ~48 GFLOP, floor ~305 us.
//
// R3 changes:
//  - REVERT build to R1's separate build_unitaries + prep_weights (R2's merged version
//    regressed ~100us -> ~500us; R1 structure measured fast).
//  - Main: 2 samples/thread (128 samples/block). Same wave-uniform U s_load per j now
//    feeds 128 FMAs (was 64) -> halves latency exposure per FLOP. Field stored as
//    interleaved float2 in LDS (ds_read_b64, conflict-free). LDS 65KB -> 2 blocks/CU.
//  - Layer 0 reads only .x (input real); imag slots never initialized (dead until nofu).

#define NN 64
#define LL 5
#define NMZI 2016            // 64*63/2
#define C_HALF 0.7071067811865476f
#define GAMMA_ 0.05f
#define SENSRESP 0.0008f     // SENS*RESP

// workspace layout (float offsets)
#define UC_OFF   0                 // UC[l][c][r] float2: U[r][c]*e^{i psi_r}; 40960
#define W1T_OFF  40960             // W1T[j][r]  (64 x 128)
#define W2T_OFF  49152             // W2T[j][r]  (128 x 64)
#define W3T_OFF  57344             // W3T[j][r]  (64 x 12)
#define NOFU_OFF 58112             // 4*64 x float4 (sb, sq*gamma, d0, 0)

// ---------------------------------------------------------------------------
// Kernel 1 (R1 verbatim): one block per layer, 64 threads; thread = column c,
// 2016-step Givens scan fully unrolled in registers.
// ---------------------------------------------------------------------------
__global__ __launch_bounds__(64) void build_unitaries(
    const float* __restrict__ mzi, const float* __restrict__ oph,
    float* __restrict__ ws)
{
    const int l = blockIdx.x;
    const int c = threadIdx.x;

    __shared__ float cs[NMZI][4];   // {cos(phi), sin(phi), C*cos(th), C*sin(th)}
    __shared__ float ocs[NN][2];    // {cos(psi), sin(psi)}

    for (int m = c; m < NMZI; m += 64) {
        float th = mzi[l * 2 * NMZI + 2 * m];
        float ph = mzi[l * 2 * NMZI + 2 * m + 1];
        float sth, cth, sph, cph;
        sincosf(th, &sth, &cth);
        sincosf(ph, &sph, &cph);
        cs[m][0] = cph; cs[m][1] = sph;
        cs[m][2] = C_HALF * cth; cs[m][3] = C_HALF * sth;
    }
    {
        float ps = oph[l * NN + c];
        float sp, cp; sincosf(ps, &sp, &cp);
        ocs[c][0] = cp; ocs[c][1] = sp;
    }
    __syncthreads();

    float ur[NN], ui[NN];
    #pragma unroll
    for (int r = 0; r < NN; ++r) { ur[r] = (r == c) ? 1.f : 0.f; ui[r] = 0.f; }

    int m = 0;
    #pragma unroll
    for (int i = 0; i < NN - 1; ++i) {
        #pragma unroll
        for (int j = i + 1; j < NN; ++j) {
            float cph = cs[m][0], sph = cs[m][1];
            float cct = cs[m][2], cst = cs[m][3];
            float tr = cph * ur[j] - sph * ui[j];
            float ti = cph * ui[j] + sph * ur[j];
            float ar = ur[i] + tr, ai = ui[i] + ti;
            float sr = ur[i] - tr, si = ui[i] - ti;
            ur[i] = C_HALF * ar;
            ui[i] = C_HALF * ai;
            ur[j] = cct * sr - cst * si;
            ui[j] = cct * si + cst * sr;
            ++m;
        }
    }

    float* UCl = ws + UC_OFF + (l * NN + c) * NN * 2;
    #pragma unroll
    for (int r = 0; r < NN; ++r) {
        float cp = ocs[r][0], sp = ocs[r][1];
        UCl[2 * r]     = cp * ur[r] - sp * ui[r];
        UCl[2 * r + 1] = cp * ui[r] + sp * ur[r];
    }
}

// ---------------------------------------------------------------------------
// Kernel 2: weight transposes + nofu per-row constants (tiny).
// ---------------------------------------------------------------------------
__global__ void prep_weights(const float* __restrict__ W1,
                             const float* __restrict__ W2,
                             const float* __restrict__ W3,
                             const float* __restrict__ beta_param,
                             const float* __restrict__ det0,
                             float* __restrict__ ws)
{
    int idx = blockIdx.x * 256 + threadIdx.x;
    if (idx < 8192) {                       // W1 (128,64) -> W1T[j][r]
        int r = idx >> 6, j = idx & 63;
        ws[W1T_OFF + j * 128 + r] = W1[idx];
    } else if (idx < 16384) {               // W2 (64,128) -> W2T[j][r]
        int t = idx - 8192;
        int r = t >> 7, j = t & 127;
        ws[W2T_OFF + j * 64 + r] = W2[t];
    } else if (idx < 17152) {               // W3 (12,64) -> W3T[j][r]
        int t = idx - 16384;
        int r = t >> 6, j = t & 63;
        ws[W3T_OFF + j * 12 + r] = W3[t];
    } else if (idx < 17408) {               // nofu constants, t = l*64+row
        int t = idx - 17152;
        float bp = beta_param[t];
        float beta = 1.f / (1.f + expf(-bp));
        float* p = ws + NOFU_OFF + t * 4;
        p[0] = SENSRESP * beta;
        p[1] = sqrtf(fmaxf(1.f - beta, 0.f)) * GAMMA_;
        p[2] = det0[t];
        p[3] = 0.f;
    }
}

// ---------------------------------------------------------------------------
// Kernel 3: main. 128 samples/block, 256 threads; thread = (sample s, s+64) x
// rows [16w,16w+16). Field: interleaved float2 in LDS, row stride 129 f2
// (conflict-free b64). U rows wave-uniform -> s_load, shared across 2 samples.
// ---------------------------------------------------------------------------
__global__ __launch_bounds__(256, 2) void ficonn_main(
    const float* __restrict__ x,
    const float* __restrict__ b1,
    const float* __restrict__ b2,
    const float* __restrict__ b3,
    const float* __restrict__ ws,
    float* __restrict__ out)
{
    __shared__ float buf[16640];            // 65 KB
    float2* f2 = (float2*)buf;              // field: f2[j*129 + s], j<64, s<128
    float*  pw = buf;                       // power/h2: pw[j*130 + s]
    float*  hb = buf + 8320;                // h1 half:  hb[j*130 + s]

    const int s = threadIdx.x & 63;
    const int w = __builtin_amdgcn_readfirstlane(threadIdx.x >> 6);
    const int base = blockIdx.x * 128;

    // load x tile (32 KB, float4), write only .x of field (imag dead until nofu)
    {
        const float4* x4 = (const float4*)(x + (size_t)base * 64);
        #pragma unroll
        for (int it = 0; it < 8; ++it) {
            int idx = threadIdx.x + it * 256;   // = ss*16 + j4
            int j4 = idx & 15, ss = idx >> 4;
            float4 v = x4[idx];
            f2[(4 * j4 + 0) * 129 + ss].x = v.x;
            f2[(4 * j4 + 1) * 129 + ss].x = v.y;
            f2[(4 * j4 + 2) * 129 + ss].x = v.z;
            f2[(4 * j4 + 3) * 129 + ss].x = v.w;
        }
    }
    __syncthreads();

    float ar0[16], ai0[16], ar1[16], ai1[16];
    const float* UC = ws + UC_OFF;
    const float4* nofuC = (const float4*)(ws + NOFU_OFF);

    // ---- layer 0: input real -> 64 FMA/j ----
    {
        #pragma unroll
        for (int k = 0; k < 16; ++k) { ar0[k]=0.f; ai0[k]=0.f; ar1[k]=0.f; ai1[k]=0.f; }
        const float* Ul = UC + w * 32;
        #pragma unroll 2
        for (int j = 0; j < 64; ++j) {
            float f0 = f2[j * 129 + s].x;
            float f1 = f2[j * 129 + s + 64].x;
            const float* Uj = Ul + j * 128;
            #pragma unroll
            for (int k = 0; k < 16; ++k) {
                float cr = Uj[2 * k], ci = Uj[2 * k + 1];
                ar0[k] = fmaf(cr, f0, ar0[k]);
                ai0[k] = fmaf(ci, f0, ai0[k]);
                ar1[k] = fmaf(cr, f1, ar1[k]);
                ai1[k] = fmaf(ci, f1, ai1[k]);
            }
        }
        __syncthreads();
        #pragma unroll
        for (int k = 0; k < 16; ++k) {
            int row = w * 16 + k;
            float4 nc = nofuC[row];
            float p0   = fmaf(ar0[k], ar0[k], ai0[k] * ai0[k]);
            float det0_ = fmaf(nc.x, p0, nc.z);
            float sc0  = nc.y * __builtin_amdgcn_rcpf(fmaf(det0_, det0_, GAMMA_ * GAMMA_));
            float p1   = fmaf(ar1[k], ar1[k], ai1[k] * ai1[k]);
            float det1_ = fmaf(nc.x, p1, nc.z);
            float sc1  = nc.y * __builtin_amdgcn_rcpf(fmaf(det1_, det1_, GAMMA_ * GAMMA_));
            f2[row * 129 + s]      = make_float2(sc0 * fmaf( det0_, ai0[k], GAMMA_ * ar0[k]),
                                                 sc0 * fmaf(-det0_, ar0[k], GAMMA_ * ai0[k]));
            f2[row * 129 + s + 64] = make_float2(sc1 * fmaf( det1_, ai1[k], GAMMA_ * ar1[k]),
                                                 sc1 * fmaf(-det1_, ar1[k], GAMMA_ * ai1[k]));
        }
        __syncthreads();
    }

    // ---- layers 1..4: complex matvec, 128 FMA per j per thread ----
    for (int l = 1; l < LL; ++l) {
        #pragma unroll
        for (int k = 0; k < 16; ++k) { ar0[k]=0.f; ai0[k]=0.f; ar1[k]=0.f; ai1[k]=0.f; }
        const float* Ul = UC + l * 8192 + w * 32;
        #pragma unroll 2
        for (int j = 0; j < 64; ++j) {
            float2 f0 = f2[j * 129 + s];
            float2 f1 = f2[j * 129 + s + 64];
            const float* Uj = Ul + j * 128;         // wave-uniform, contiguous
            #pragma unroll
            for (int k = 0; k < 16; ++k) {
                float cr = Uj[2 * k], ci = Uj[2 * k + 1];
                ar0[k] = fmaf(cr, f0.x, fmaf(-ci, f0.y, ar0[k]));
                ai0[k] = fmaf(cr, f0.y, fmaf( ci, f0.x, ai0[k]));
                ar1[k] = fmaf(cr, f1.x, fmaf(-ci, f1.y, ar1[k]));
                ai1[k] = fmaf(cr, f1.y, fmaf( ci, f1.x, ai1[k]));
            }
        }
        __syncthreads();   // all field reads done before overwrite

        if (l < LL - 1) {
            #pragma unroll
            for (int k = 0; k < 16; ++k) {
                int row = w * 16 + k;
                float4 nc = nofuC[l * 64 + row];
                float p0   = fmaf(ar0[k], ar0[k], ai0[k] * ai0[k]);
                float det0_ = fmaf(nc.x, p0, nc.z);
                float sc0  = nc.y * __builtin_amdgcn_rcpf(fmaf(det0_, det0_, GAMMA_ * GAMMA_));
                float p1   = fmaf(ar1[k], ar1[k], ai1[k] * ai1[k]);
                float det1_ = fmaf(nc.x, p1, nc.z);
                float sc1  = nc.y * __builtin_amdgcn_rcpf(fmaf(det1_, det1_, GAMMA_ * GAMMA_));
                f2[row * 129 + s]      = make_float2(sc0 * fmaf( det0_, ai0[k], GAMMA_ * ar0[k]),
                                                     sc0 * fmaf(-det0_, ar0[k], GAMMA_ * ai0[k]));
                f2[row * 129 + s + 64] = make_float2(sc1 * fmaf( det1_, ai1[k], GAMMA_ * ar1[k]),
                                                     sc1 * fmaf(-det1_, ar1[k], GAMMA_ * ai1[k]));
            }
        } else {
            #pragma unroll
            for (int k = 0; k < 16; ++k) {
                int row = w * 16 + k;
                pw[row * 130 + s]      = fmaf(ar0[k], ar0[k], ai0[k] * ai0[k]);
                pw[row * 130 + s + 64] = fmaf(ar1[k], ar1[k], ai1[k] * ai1[k]);
            }
        }
        __syncthreads();
    }

    // ---- MLP ----
    float g0[16], g1[16];
    #pragma unroll
    for (int k = 0; k < 16; ++k) { g0[k] = 0.f; g1[k] = 0.f; }

    #pragma unroll 1
    for (int half = 0; half < 2; ++half) {
        float h0[16], h1_[16];
        #pragma unroll
        for (int k = 0; k < 16; ++k) { h0[k] = 0.f; h1_[k] = 0.f; }
        const float* W1Tp = ws + W1T_OFF + 64 * half + w * 16;
        #pragma unroll 2
        for (int j = 0; j < 64; ++j) {
            float f0 = pw[j * 130 + s];
            float f1 = pw[j * 130 + s + 64];
            const float* r_ = W1Tp + j * 128;
            #pragma unroll
            for (int k = 0; k < 16; ++k) {
                h0[k] = fmaf(r_[k], f0, h0[k]);
                h1_[k] = fmaf(r_[k], f1, h1_[k]);
            }
        }
        #pragma unroll
        for (int k = 0; k < 16; ++k) {
            float bias = b1[64 * half + w * 16 + k];
            hb[(w * 16 + k) * 130 + s]      = fmaxf(h0[k] + bias, 0.f);
            hb[(w * 16 + k) * 130 + s + 64] = fmaxf(h1_[k] + bias, 0.f);
        }
        __syncthreads();                            // h1 half ready

        const float* W2Tp = ws + W2T_OFF + (64 * half) * 64 + w * 16;
        #pragma unroll 2
        for (int j = 0; j < 64; ++j) {
            float f0 = hb[j * 130 + s];
            float f1 = hb[j * 130 + s + 64];
            const float* r_ = W2Tp + j * 64;
            #pragma unroll
            for (int k = 0; k < 16; ++k) {
                g0[k] = fmaf(r_[k], f0, g0[k]);
                g1[k] = fmaf(r_[k], f1, g1[k]);
            }
        }
        __syncthreads();                            // hb (and pw after half 1) free
    }

    // h2 -> pw (power dead)
    #pragma unroll
    for (int k = 0; k < 16; ++k) {
        float bias = b2[w * 16 + k];
        pw[(w * 16 + k) * 130 + s]      = fmaxf(g0[k] + bias, 0.f);
        pw[(w * 16 + k) * 130 + s + 64] = fmaxf(g1[k] + bias, 0.f);
    }
    __syncthreads();

    // out = W3 @ h2 + b3: wave w -> rows [3w, 3w+3)
    {
        float o0a = 0.f, o1a = 0.f, o2a = 0.f;
        float o0b = 0.f, o1b = 0.f, o2b = 0.f;
        const float* W3T = ws + W3T_OFF + w * 3;
        #pragma unroll 4
        for (int j = 0; j < 64; ++j) {
            float f0 = pw[j * 130 + s];
            float f1 = pw[j * 130 + s + 64];
            const float* r_ = W3T + j * 12;
            o0a = fmaf(r_[0], f0, o0a); o0b = fmaf(r_[0], f1, o0b);
            o1a = fmaf(r_[1], f0, o1a); o1b = fmaf(r_[1], f1, o1b);
            o2a = fmaf(r_[2], f0, o2a); o2b = fmaf(r_[2], f1, o2b);
        }
        float* opa = out + (size_t)(base + s) * 12 + w * 3;
        float* opb = out + (size_t)(base + s + 64) * 12 + w * 3;
        opa[0] = o0a + b3[w * 3 + 0];
        opa[1] = o1a + b3[w * 3 + 1];
        opa[2] = o2a + b3[w * 3 + 2];
        opb[0] = o0b + b3[w * 3 + 0];
        opb[1] = o1b + b3[w * 3 + 1];
        opb[2] = o2b + b3[w * 3 + 2];
    }
}

extern "C" void kernel_launch(void* const* d_in, const int* in_sizes, int n_in,
                              void* d_out, int out_size, void* d_ws, size_t ws_size,
                              hipStream_t stream)
{
    const float* x    = (const float*)d_in[0];
    const float* mzi  = (const float*)d_in[1];
    const float* oph  = (const float*)d_in[2];
    const float* beta = (const float*)d_in[3];
    const float* det0 = (const float*)d_in[4];
    const float* W1   = (const float*)d_in[5];
    const float* b1   = (const float*)d_in[6];
    const float* W2   = (const float*)d_in[7];
    const float* b2   = (const float*)d_in[8];
    const float* W3   = (const float*)d_in[9];
    const float* b3   = (const float*)d_in[10];
    float* ws  = (float*)d_ws;
    float* out = (float*)d_out;

    const int B = in_sizes[0] / NN;       // 262144
    const int blocks = B / 128;           // 2048

    hipLaunchKernelGGL(build_unitaries, dim3(LL), dim3(64), 0, stream, mzi, oph, ws);
    hipLaunchKernelGGL(prep_weights, dim3(68), dim3(256), 0, stream,
                       W1, W2, W3, beta, det0, ws);
    hipLaunchKernelGGL(ficonn_main, dim3(blocks), dim3(256), 0, stream,
                       x, b1, b2, b3, ws, out);
}

// Round 4
// 376.494 us; speedup vs baseline: 3.1691x; 2.6859x over previous
//
#include <hip/hip_runtime.h>
#include <math.h>

// FICONN forward via split-bf16 MFMA (hi+lo, 3-product) for the 5 complex unitary
// layers + W1/W2 of the MLP; W3 fp32 VALU. fp32 path plateaued ~700us (issue-bound);
// bf16 MFMA floor is ~75us of matrix work.
//
// Layouts (m89-verified gfx950 16x16x32 bf16):
//   C/D: col(N) = lane&15, row(M) = (lane>>4)*4 + reg
//   A:   m = lane&15, k = (lane>>4)*8 + j   (8 consecutive k per lane)
//   B:   n = lane&15, k = (lane>>4)*8 + j
// Activations F in LDS: packed uint (bf16 hi | lo<<16), F[n][k], row stride 132
// (b128 starts spread over stride-4 banks, 8 lanes each -> balanced).
// A-fragments pre-linearized in ws: wave load = contiguous 1KB dwordx4 (vmcnt).

#define NN 64
#define LL 5
#define NMZI 2016
#define C_HALF 0.7071067811865476f
#define GAMMA_ 0.05f
#define SENSRESP 0.0008f     // SENS*RESP

// ws layout:
//   AH (ushort) at byte 0,      7 slots * 8Mt * 4Kt * 512 = 114688 shorts
//   AL (ushort) at short 114688
//   floats at byte 458752: nofuC (256 float4 = 1024 floats), W3T (768 floats)
#define AH_SHORTS   114688
#define FLOAT_BYTE  458752

typedef short short8 __attribute__((ext_vector_type(8)));
typedef float f32x4  __attribute__((ext_vector_type(4)));

__device__ __forceinline__ unsigned short f2bf(float f) {
    unsigned u = __float_as_uint(f);
    unsigned r = u + 0x7fffu + ((u >> 16) & 1u);
    return (unsigned short)(r >> 16);
}
__device__ __forceinline__ float bf2f(unsigned short h) {
    return __uint_as_float(((unsigned)h) << 16);
}
__device__ __forceinline__ unsigned packsplit(float v) {
    unsigned short h = f2bf(v);
    float lo = v - bf2f(h);
    return (unsigned)h | (((unsigned)f2bf(lo)) << 16);
}
// frag-linear offset (in shorts) of element (m,k) of A-slot l
__device__ __forceinline__ int afrag_off(int l, int m, int k) {
    return ((((l * 8 + (m >> 4)) * 4 + (k >> 5)) << 9)
          + ((((k >> 3) & 3) * 16 + (m & 15)) << 3) + (k & 7));
}

// ---------------------------------------------------------------------------
// Kernel 1: build the 5 unitaries (R1-proven scan structure), store as split
// bf16 A-fragments of Mat = [[Ur,-Ui],[Ui,Ur]] (output phases folded).
// ---------------------------------------------------------------------------
__global__ __launch_bounds__(64) void build_unitaries(
    const float* __restrict__ mzi, const float* __restrict__ oph,
    unsigned short* __restrict__ AH)
{
    unsigned short* AL = AH + AH_SHORTS;
    const int l = blockIdx.x;
    const int c = threadIdx.x;

    __shared__ float cs[NMZI][4];
    __shared__ float ocs[NN][2];

    for (int m = c; m < NMZI; m += 64) {
        float th = mzi[l * 2 * NMZI + 2 * m];
        float ph = mzi[l * 2 * NMZI + 2 * m + 1];
        float sth, cth, sph, cph;
        sincosf(th, &sth, &cth);
        sincosf(ph, &sph, &cph);
        cs[m][0] = cph; cs[m][1] = sph;
        cs[m][2] = C_HALF * cth; cs[m][3] = C_HALF * sth;
    }
    {
        float ps = oph[l * NN + c];
        float sp, cp; sincosf(ps, &sp, &cp);
        ocs[c][0] = cp; ocs[c][1] = sp;
    }
    __syncthreads();

    float ur[NN], ui[NN];
    #pragma unroll
    for (int r = 0; r < NN; ++r) { ur[r] = (r == c) ? 1.f : 0.f; ui[r] = 0.f; }

    int m = 0;
    #pragma unroll
    for (int i = 0; i < NN - 1; ++i) {
        #pragma unroll
        for (int j = i + 1; j < NN; ++j) {
            float cph = cs[m][0], sph = cs[m][1];
            float cct = cs[m][2], cst = cs[m][3];
            float tr = cph * ur[j] - sph * ui[j];
            float ti = cph * ui[j] + sph * ur[j];
            float ar = ur[i] + tr, ai = ui[i] + ti;
            float sr = ur[i] - tr, si = ui[i] - ti;
            ur[i] = C_HALF * ar;
            ui[i] = C_HALF * ai;
            ur[j] = cct * sr - cst * si;
            ui[j] = cct * si + cst * sr;
            ++m;
        }
    }
    // fold output phases: U[r][c] *= e^{i psi_r}
    #pragma unroll
    for (int r = 0; r < NN; ++r) {
        float cp = ocs[r][0], sp = ocs[r][1];
        float vr = cp * ur[r] - sp * ui[r];
        float vi = cp * ui[r] + sp * ur[r];
        ur[r] = vr; ui[r] = vi;
    }
    // thread c owns Mat columns k=c (Ur;Ui) and k=c+64 (-Ui;Ur)
    #pragma unroll
    for (int mm = 0; mm < 128; ++mm) {
        float v1 = (mm < 64) ? ur[mm] : ui[mm - 64];
        float v2 = (mm < 64) ? -ui[mm] : ur[mm - 64];
        int o1 = afrag_off(l, mm, c);
        int o2 = afrag_off(l, mm, c + 64);
        unsigned short h1 = f2bf(v1), h2 = f2bf(v2);
        AH[o1] = h1; AL[o1] = f2bf(v1 - bf2f(h1));
        AH[o2] = h2; AL[o2] = f2bf(v2 - bf2f(h2));
    }
}

// ---------------------------------------------------------------------------
// Kernel 2: W1 -> A-slot 5, W2 -> A-slot 6 (split bf16 frags), W3T, nofu consts.
// ---------------------------------------------------------------------------
__global__ void prep_weights(const float* __restrict__ W1,
                             const float* __restrict__ W2,
                             const float* __restrict__ W3,
                             const float* __restrict__ beta_param,
                             const float* __restrict__ det0,
                             unsigned short* __restrict__ AH)
{
    unsigned short* AL = AH + AH_SHORTS;
    float* fbase = (float*)((char*)AH + FLOAT_BYTE);
    float* nofuF = fbase;               // 1024 floats (256 x float4)
    float* W3T   = fbase + 1024;        // 768 floats

    int idx = blockIdx.x * 256 + threadIdx.x;
    if (idx < 8192) {                        // W1 (128x64): m=idx>>6, k=idx&63
        int mm = idx >> 6, k = idx & 63;
        float v = W1[idx];
        unsigned short h = f2bf(v);
        int o = afrag_off(5, mm, k);
        AH[o] = h; AL[o] = f2bf(v - bf2f(h));
    } else if (idx < 16384) {                // W2 (64x128): m=t>>7, k=t&127
        int t = idx - 8192;
        int mm = t >> 7, k = t & 127;
        float v = W2[t];
        unsigned short h = f2bf(v);
        int o = afrag_off(6, mm, k);
        AH[o] = h; AL[o] = f2bf(v - bf2f(h));
    } else if (idx < 17152) {                // W3 (12x64) -> W3T[j][r]
        int t = idx - 16384;
        int r = t >> 6, j = t & 63;
        W3T[j * 12 + r] = W3[t];
    } else if (idx < 17408) {                // nofu consts, t = l*64+row
        int t = idx - 17152;
        float bp = beta_param[t];
        float beta = 1.f / (1.f + expf(-bp));
        float* p = nofuF + t * 4;
        p[0] = SENSRESP * beta;
        p[1] = sqrtf(fmaxf(1.f - beta, 0.f)) * GAMMA_;
        p[2] = det0[t];
        p[3] = 0.f;
    }
}

// ---------------------------------------------------------------------------
// Kernel 3: main. 128 samples/block, 256 threads (4 waves).
// wave w: mp=w&1 (M half), nh=w>>1 (N half: samples 64*nh..64*nh+64).
// ---------------------------------------------------------------------------
#define FS 132

__global__ __launch_bounds__(256, 2) void ficonn_main(
    const float* __restrict__ x,
    const float* __restrict__ b1,
    const float* __restrict__ b2,
    const float* __restrict__ b3,
    const unsigned short* __restrict__ AH,
    const float4* __restrict__ nofuC,
    const float* __restrict__ W3T,
    float* __restrict__ out)
{
    const unsigned short* AL = AH + AH_SHORTS;
    __shared__ __align__(16) unsigned F[128 * FS];   // 67.6 KB

    const int tid  = threadIdx.x;
    const int lane = tid & 63;
    const int w    = tid >> 6;
    const int mp   = w & 1, nh = w >> 1;
    const int n16  = lane & 15, q = lane >> 4;
    const int base = blockIdx.x * 128;

    // ---- stage x: pack split-bf16 into F[n][k], k<64 (input is real) ----
    {
        const float4* x4 = (const float4*)(x + (size_t)base * 64);
        #pragma unroll
        for (int it = 0; it < 8; ++it) {
            int idx = tid + it * 256;
            int j4 = idx & 15, ss = idx >> 4;
            float4 v = x4[idx];
            uint4 pk = make_uint4(packsplit(v.x), packsplit(v.y),
                                  packsplit(v.z), packsplit(v.w));
            *(uint4*)&F[ss * FS + 4 * j4] = pk;
        }
    }
    __syncthreads();

    f32x4 acc[4][4];

    // ================= 5 unitary layers =================
    for (int l = 0; l < 5; ++l) {
        #pragma unroll
        for (int i = 0; i < 4; ++i)
            #pragma unroll
            for (int t = 0; t < 4; ++t)
                #pragma unroll
                for (int r = 0; r < 4; ++r) acc[i][t][r] = 0.f;

        const int K4 = (l == 0) ? 2 : 4;   // layer 0: imag input = 0
        for (int Kt = 0; Kt < K4; ++Kt) {
            uint4 ahu[4], alu[4];
            #pragma unroll
            for (int i = 0; i < 4; ++i) {
                int Mt = 2 * mp + (i & 1) + 4 * (i >> 1);   // {2mp,2mp+1,2mp+4,2mp+5}
                int off = (((l * 8 + Mt) * 4 + Kt) << 9);
                ahu[i] = ((const uint4*)(AH + off))[lane];
                alu[i] = ((const uint4*)(AL + off))[lane];
            }
            uint4 bq0[4], bq1[4];
            #pragma unroll
            for (int t = 0; t < 4; ++t) {
                int n = 64 * nh + 16 * t + n16;
                const uint4* p = (const uint4*)&F[n * FS + 32 * Kt + 8 * q];
                bq0[t] = p[0]; bq1[t] = p[1];
            }
            #pragma unroll
            for (int t = 0; t < 4; ++t) {
                union { short8 s; unsigned u[4]; } bh, bl;
                unsigned uu[8] = {bq0[t].x, bq0[t].y, bq0[t].z, bq0[t].w,
                                  bq1[t].x, bq1[t].y, bq1[t].z, bq1[t].w};
                #pragma unroll
                for (int e = 0; e < 4; ++e) {
                    unsigned a = uu[2 * e], b = uu[2 * e + 1];
                    bh.u[e] = (a & 0xffffu) | (b << 16);
                    bl.u[e] = (a >> 16) | (b & 0xffff0000u);
                }
                #pragma unroll
                for (int i = 0; i < 4; ++i) {
                    union { short8 s; uint4 u4; } ah_, al_;
                    ah_.u4 = ahu[i]; al_.u4 = alu[i];
                    acc[i][t] = __builtin_amdgcn_mfma_f32_16x16x32_bf16(ah_.s, bh.s, acc[i][t], 0, 0, 0);
                    acc[i][t] = __builtin_amdgcn_mfma_f32_16x16x32_bf16(ah_.s, bl.s, acc[i][t], 0, 0, 0);
                    acc[i][t] = __builtin_amdgcn_mfma_f32_16x16x32_bf16(al_.s, bh.s, acc[i][t], 0, 0, 0);
                }
            }
        }
        __syncthreads();   // all F reads done

        if (l < 4) {
            // nofu in C-layout regs: yr=acc[i], yi=acc[i+2] (row m and m+64, same lane)
            #pragma unroll
            for (int i = 0; i < 2; ++i) {
                int Mt = 2 * mp + i;
                float4 nc[4];
                #pragma unroll
                for (int r = 0; r < 4; ++r)
                    nc[r] = nofuC[l * 64 + 16 * Mt + 4 * q + r];
                #pragma unroll
                for (int t = 0; t < 4; ++t) {
                    int n = 64 * nh + 16 * t + n16;
                    unsigned wr[4], wi[4];
                    #pragma unroll
                    for (int r = 0; r < 4; ++r) {
                        float yr = acc[i][t][r], yi = acc[i + 2][t][r];
                        float4 c = nc[r];
                        float p   = fmaf(yr, yr, yi * yi);
                        float det = fmaf(c.x, p, c.z);
                        float sc  = c.y * __builtin_amdgcn_rcpf(fmaf(det, det, GAMMA_ * GAMMA_));
                        wr[r] = packsplit(sc * fmaf( det, yi, GAMMA_ * yr));
                        wi[r] = packsplit(sc * fmaf(-det, yr, GAMMA_ * yi));
                    }
                    int k0 = 16 * Mt + 4 * q;
                    *(uint4*)&F[n * FS + k0]      = make_uint4(wr[0], wr[1], wr[2], wr[3]);
                    *(uint4*)&F[n * FS + 64 + k0] = make_uint4(wi[0], wi[1], wi[2], wi[3]);
                }
            }
        } else {
            // power -> F[n][k<64]
            #pragma unroll
            for (int i = 0; i < 2; ++i) {
                int Mt = 2 * mp + i;
                #pragma unroll
                for (int t = 0; t < 4; ++t) {
                    int n = 64 * nh + 16 * t + n16;
                    unsigned wp[4];
                    #pragma unroll
                    for (int r = 0; r < 4; ++r) {
                        float yr = acc[i][t][r], yi = acc[i + 2][t][r];
                        wp[r] = packsplit(fmaf(yr, yr, yi * yi));
                    }
                    *(uint4*)&F[n * FS + 16 * Mt + 4 * q] = make_uint4(wp[0], wp[1], wp[2], wp[3]);
                }
            }
        }
        __syncthreads();
    }

    // ================= W1: M=128, K=64 (slot 5) =================
    {
        #pragma unroll
        for (int i = 0; i < 4; ++i)
            #pragma unroll
            for (int t = 0; t < 4; ++t)
                #pragma unroll
                for (int r = 0; r < 4; ++r) acc[i][t][r] = 0.f;

        for (int Kt = 0; Kt < 2; ++Kt) {
            uint4 ahu[4], alu[4];
            #pragma unroll
            for (int i = 0; i < 4; ++i) {
                int Mt = 4 * mp + i;
                int off = (((5 * 8 + Mt) * 4 + Kt) << 9);
                ahu[i] = ((const uint4*)(AH + off))[lane];
                alu[i] = ((const uint4*)(AL + off))[lane];
            }
            uint4 bq0[4], bq1[4];
            #pragma unroll
            for (int t = 0; t < 4; ++t) {
                int n = 64 * nh + 16 * t + n16;
                const uint4* p = (const uint4*)&F[n * FS + 32 * Kt + 8 * q];
                bq0[t] = p[0]; bq1[t] = p[1];
            }
            #pragma unroll
            for (int t = 0; t < 4; ++t) {
                union { short8 s; unsigned u[4]; } bh, bl;
                unsigned uu[8] = {bq0[t].x, bq0[t].y, bq0[t].z, bq0[t].w,
                                  bq1[t].x, bq1[t].y, bq1[t].z, bq1[t].w};
                #pragma unroll
                for (int e = 0; e < 4; ++e) {
                    unsigned a = uu[2 * e], b = uu[2 * e + 1];
                    bh.u[e] = (a & 0xffffu) | (b << 16);
                    bl.u[e] = (a >> 16) | (b & 0xffff0000u);
                }
                #pragma unroll
                for (int i = 0; i < 4; ++i) {
                    union { short8 s; uint4 u4; } ah_, al_;
                    ah_.u4 = ahu[i]; al_.u4 = alu[i];
                    acc[i][t] = __builtin_amdgcn_mfma_f32_16x16x32_bf16(ah_.s, bh.s, acc[i][t], 0, 0, 0);
                    acc[i][t] = __builtin_amdgcn_mfma_f32_16x16x32_bf16(ah_.s, bl.s, acc[i][t], 0, 0, 0);
                    acc[i][t] = __builtin_amdgcn_mfma_f32_16x16x32_bf16(al_.s, bh.s, acc[i][t], 0, 0, 0);
                }
            }
        }
        __syncthreads();

        // relu(acc + b1) -> F[n][k=row], k in [0,128)
        #pragma unroll
        for (int i = 0; i < 4; ++i) {
            int Mt = 4 * mp + i;
            float4 bb = *(const float4*)&b1[16 * Mt + 4 * q];
            #pragma unroll
            for (int t = 0; t < 4; ++t) {
                int n = 64 * nh + 16 * t + n16;
                unsigned wv[4];
                #pragma unroll
                for (int r = 0; r < 4; ++r) {
                    float h = fmaxf(acc[i][t][r] + ((const float*)&bb)[r], 0.f);
                    wv[r] = packsplit(h);
                }
                *(uint4*)&F[n * FS + 16 * Mt + 4 * q] = make_uint4(wv[0], wv[1], wv[2], wv[3]);
            }
        }
        __syncthreads();
    }

    // ================= W2: M=64, K=128 (slot 6) =================
    {
        #pragma unroll
        for (int i = 0; i < 2; ++i)
            #pragma unroll
            for (int t = 0; t < 4; ++t)
                #pragma unroll
                for (int r = 0; r < 4; ++r) acc[i][t][r] = 0.f;

        for (int Kt = 0; Kt < 4; ++Kt) {
            uint4 ahu[2], alu[2];
            #pragma unroll
            for (int i = 0; i < 2; ++i) {
                int Mt = 2 * mp + i;
                int off = (((6 * 8 + Mt) * 4 + Kt) << 9);
                ahu[i] = ((const uint4*)(AH + off))[lane];
                alu[i] = ((const uint4*)(AL + off))[lane];
            }
            uint4 bq0[4], bq1[4];
            #pragma unroll
            for (int t = 0; t < 4; ++t) {
                int n = 64 * nh + 16 * t + n16;
                const uint4* p = (const uint4*)&F[n * FS + 32 * Kt + 8 * q];
                bq0[t] = p[0]; bq1[t] = p[1];
            }
            #pragma unroll
            for (int t = 0; t < 4; ++t) {
                union { short8 s; unsigned u[4]; } bh, bl;
                unsigned uu[8] = {bq0[t].x, bq0[t].y, bq0[t].z, bq0[t].w,
                                  bq1[t].x, bq1[t].y, bq1[t].z, bq1[t].w};
                #pragma unroll
                for (int e = 0; e < 4; ++e) {
                    unsigned a = uu[2 * e], b = uu[2 * e + 1];
                    bh.u[e] = (a & 0xffffu) | (b << 16);
                    bl.u[e] = (a >> 16) | (b & 0xffff0000u);
                }
                #pragma unroll
                for (int i = 0; i < 2; ++i) {
                    union { short8 s; uint4 u4; } ah_, al_;
                    ah_.u4 = ahu[i]; al_.u4 = alu[i];
                    acc[i][t] = __builtin_amdgcn_mfma_f32_16x16x32_bf16(ah_.s, bh.s, acc[i][t], 0, 0, 0);
                    acc[i][t] = __builtin_amdgcn_mfma_f32_16x16x32_bf16(ah_.s, bl.s, acc[i][t], 0, 0, 0);
                    acc[i][t] = __builtin_amdgcn_mfma_f32_16x16x32_bf16(al_.s, bh.s, acc[i][t], 0, 0, 0);
                }
            }
        }
        __syncthreads();

        // relu(acc + b2) -> F[n][k<64]
        #pragma unroll
        for (int i = 0; i < 2; ++i) {
            int Mt = 2 * mp + i;
            float4 bb = *(const float4*)&b2[16 * Mt + 4 * q];
            #pragma unroll
            for (int t = 0; t < 4; ++t) {
                int n = 64 * nh + 16 * t + n16;
                unsigned wv[4];
                #pragma unroll
                for (int r = 0; r < 4; ++r) {
                    float h = fmaxf(acc[i][t][r] + ((const float*)&bb)[r], 0.f);
                    wv[r] = packsplit(h);
                }
                *(uint4*)&F[n * FS + 16 * Mt + 4 * q] = make_uint4(wv[0], wv[1], wv[2], wv[3]);
            }
        }
        __syncthreads();
    }

    // ================= W3: fp32 VALU, thread = sample =================
    if (tid < 128) {
        int n = tid;
        float o[12];
        #pragma unroll
        for (int r = 0; r < 12; ++r) o[r] = b3[r];
        #pragma unroll
        for (int kc = 0; kc < 16; ++kc) {
            uint4 pk = *(const uint4*)&F[n * FS + 4 * kc];
            unsigned uu[4] = {pk.x, pk.y, pk.z, pk.w};
            #pragma unroll
            for (int e = 0; e < 4; ++e) {
                int k = 4 * kc + e;
                float h = bf2f((unsigned short)(uu[e] & 0xffffu))
                        + bf2f((unsigned short)(uu[e] >> 16));
                const float* wr = W3T + k * 12;
                #pragma unroll
                for (int r = 0; r < 12; ++r) o[r] = fmaf(wr[r], h, o[r]);
            }
        }
        float4* op = (float4*)(out + (size_t)(base + n) * 12);
        op[0] = make_float4(o[0], o[1], o[2],  o[3]);
        op[1] = make_float4(o[4], o[5], o[6],  o[7]);
        op[2] = make_float4(o[8], o[9], o[10], o[11]);
    }
}

extern "C" void kernel_launch(void* const* d_in, const int* in_sizes, int n_in,
                              void* d_out, int out_size, void* d_ws, size_t ws_size,
                              hipStream_t stream)
{
    const float* x    = (const float*)d_in[0];
    const float* mzi  = (const float*)d_in[1];
    const float* oph  = (const float*)d_in[2];
    const float* beta = (const float*)d_in[3];
    const float* det0 = (const float*)d_in[4];
    const float* W1   = (const float*)d_in[5];
    const float* b1   = (const float*)d_in[6];
    const float* W2   = (const float*)d_in[7];
    const float* b2   = (const float*)d_in[8];
    const float* W3   = (const float*)d_in[9];
    const float* b3   = (const float*)d_in[10];
    float* out = (float*)d_out;

    unsigned short* AH = (unsigned short*)d_ws;
    float* fbase = (float*)((char*)d_ws + FLOAT_BYTE);
    const float4* nofuC = (const float4*)fbase;
    const float* W3T = fbase + 1024;

    const int B = in_sizes[0] / NN;       // 262144
    const int blocks = B / 128;           // 2048

    hipLaunchKernelGGL(build_unitaries, dim3(LL), dim3(64), 0, stream, mzi, oph, AH);
    hipLaunchKernelGGL(prep_weights, dim3(68), dim3(256), 0, stream,
                       W1, W2, W3, beta, det0, AH);
    hipLaunchKernelGGL(ficonn_main, dim3(blocks), dim3(256), 0, stream,
                       x, b1, b2, b3, AH, nofuC, W3T, out);
}